// Round 5
// baseline (314.954 us; speedup 1.0000x reference)
//
#include <hip/hip_runtime.h>
#include <stdint.h>

#define IDIM 2048
#define HDIM 2048
#define CDIM 4096
#define BDIM 4096
#define KDIM 4096

typedef float f32x4 __attribute__((ext_vector_type(4)));
typedef short s16x8 __attribute__((ext_vector_type(8)));
typedef unsigned short u16;
typedef u16 u16x8 __attribute__((ext_vector_type(8)));

__device__ __forceinline__ u16 f2bf(float f) {
    union { float f; uint32_t u; } v; v.f = f;
    uint32_t r = v.u + 0x7fffu + ((v.u >> 16) & 1u);  // round-to-nearest-even
    return (u16)(r >> 16);
}

__device__ __forceinline__ void gload_lds16(const void* g, void* l) {
    __builtin_amdgcn_global_load_lds(
        (__attribute__((address_space(1))) void*)g,
        (__attribute__((address_space(3))) void*)l,
        16, 0, 0);
}

// flat f32 -> bf16 convert, 8 elements per thread
__global__ void cvt_bf16_kernel(const float* __restrict__ src, u16* __restrict__ dst,
                                int ngroups) {
    int i = blockIdx.x * blockDim.x + threadIdx.x;
    if (i >= ngroups) return;
    const float4* s4 = (const float4*)src;
    float4 v0 = s4[2 * i], v1 = s4[2 * i + 1];
    u16x8 o;
    o[0] = f2bf(v0.x); o[1] = f2bf(v0.y); o[2] = f2bf(v0.z); o[3] = f2bf(v0.w);
    o[4] = f2bf(v1.x); o[5] = f2bf(v1.y); o[6] = f2bf(v1.z); o[7] = f2bf(v1.w);
    ((u16x8*)dst)[i] = o;
}

// combined = [x, h] as bf16 [BDIM][CDIM]; also pre-fill new_combined's x half
__global__ void pack_combined_kernel(const float* __restrict__ x, const float* __restrict__ h,
                                     u16* __restrict__ comb, u16* __restrict__ newc) {
    int i = blockIdx.x * blockDim.x + threadIdx.x;  // one group of 8 elems
    if (i >= BDIM * (CDIM / 8)) return;
    int b = i >> 9;              // CDIM/8 == 512
    int c = (i & 511) * 8;
    const float* src = (c < IDIM) ? (x + (size_t)b * IDIM + c)
                                  : (h + (size_t)b * HDIM + (c - IDIM));
    float4 v0 = ((const float4*)src)[0], v1 = ((const float4*)src)[1];
    u16x8 o;
    o[0] = f2bf(v0.x); o[1] = f2bf(v0.y); o[2] = f2bf(v0.z); o[3] = f2bf(v0.w);
    o[4] = f2bf(v1.x); o[5] = f2bf(v1.y); o[6] = f2bf(v1.z); o[7] = f2bf(v1.w);
    *(u16x8*)(comb + (size_t)b * CDIM + c) = o;
    if (c < IDIM) *(u16x8*)(newc + (size_t)b * CDIM + c) = o;
}

// ---------------------------------------------------------------------------
// GEMM1 (proven 149us / 899 TF): m97 structure, 128x128 tile, BK=64, 4 waves,
// + bijective XCD swizzle (T1): grid 1024 blocks, 8 XCDs, chunk=128, so each
// XCD owns 4 contiguous tile-rows (A-panel 4MB = one L2).
// Epilogue: v=sigmoid(acc+bias); col<HDIM -> newc[r][IDIM+col]=bf16(h*v);
//           col>=HDIM -> Sout[r][col-HDIM]=v
// ---------------------------------------------------------------------------
__global__ void gemm_bt1(const u16* __restrict__ A, const u16* __restrict__ Bm,
                         const float* __restrict__ h,
                         const float* __restrict__ bias0, const float* __restrict__ bias1,
                         float* __restrict__ Sout, u16* __restrict__ newc) {
    constexpr int BM = 128, BK = 64;
    const int tid  = threadIdx.x;
    const int lane = tid & 63;
    const int wave = tid >> 6;
    const int wr = wave >> 1, wc = wave & 1;

    // XCD-aware bijective swizzle: lin -> (lin%8)*128 + lin/8  (1024 % 8 == 0)
    const int lin = blockIdx.y * 32 + blockIdx.x;
    const int swz = (lin & 7) * 128 + (lin >> 3);
    const int bm = (swz >> 5) * BM;
    const int bn = (swz & 31) * BM;

    __shared__ __align__(16) u16 lA[BM * BK];
    __shared__ __align__(16) u16 lB[BM * BK];

    f32x4 acc[4][4] = {};

    const int srow = wave * 32 + (lane >> 3);       // staged row (per i: +8*i)
    const int sg   = (lane & 7) ^ (lane >> 3);      // swizzled source k-slot

    auto stage = [&](int k0) {
        #pragma unroll
        for (int i = 0; i < 4; ++i) {
            const int r = srow + i * 8;
            gload_lds16(A  + (size_t)(bm + r) * KDIM + k0 + sg * 8,
                        &lA[(wave * 32 + i * 8) * 64]);
            gload_lds16(Bm + (size_t)(bn + r) * KDIM + k0 + sg * 8,
                        &lB[(wave * 32 + i * 8) * 64]);
        }
    };

    stage(0);
    constexpr int NT = KDIM / BK;
    for (int kt = 0; kt < NT; ++kt) {
        __syncthreads();   // drains global_load_lds (vmcnt) + all waves ready
        #pragma unroll
        for (int ks = 0; ks < 2; ++ks) {
            s16x8 af[4], bfr[4];
            #pragma unroll
            for (int m = 0; m < 4; ++m) {
                const int row = wr * 64 + m * 16 + (lane & 15);
                const int j   = ks * 4 + (lane >> 4);
                af[m] = *(const s16x8*)&lA[row * 64 + ((j ^ (row & 7)) << 3)];
            }
            #pragma unroll
            for (int n = 0; n < 4; ++n) {
                const int row = wc * 64 + n * 16 + (lane & 15);
                const int j   = ks * 4 + (lane >> 4);
                bfr[n] = *(const s16x8*)&lB[row * 64 + ((j ^ (row & 7)) << 3)];
            }
            #pragma unroll
            for (int m = 0; m < 4; ++m)
                #pragma unroll
                for (int n = 0; n < 4; ++n)
                    acc[m][n] = __builtin_amdgcn_mfma_f32_16x16x32_bf16(
                        af[m], bfr[n], acc[m][n], 0, 0, 0);
        }
        __syncthreads();   // all reads done before restage
        if (kt + 1 < NT) stage((kt + 1) * BK);
    }

    // epilogue: D layout col = lane&15, row = (lane>>4)*4 + reg (m89-verified)
    #pragma unroll
    for (int m = 0; m < 4; ++m) {
        const int r0 = bm + wr * 64 + m * 16 + ((lane >> 4) << 2);
        #pragma unroll
        for (int n = 0; n < 4; ++n) {
            const int col = bn + wc * 64 + n * 16 + (lane & 15);
            #pragma unroll
            for (int j = 0; j < 4; ++j) {
                const int r = r0 + j;
                const float v = acc[m][n][j];
                const float bv = (col < HDIM) ? bias0[col] : bias1[col - HDIM];
                const float sgm = 1.0f / (1.0f + __expf(-(v + bv)));
                if (col < HDIM) {
                    const float hv = h[(size_t)r * HDIM + col];
                    newc[(size_t)r * CDIM + IDIM + col] = f2bf(hv * sgm);
                } else {
                    Sout[(size_t)r * HDIM + (col - HDIM)] = sgm;
                }
            }
        }
    }
}

// ---------------------------------------------------------------------------
// GEMM2 v2: BM=128, BN=64, BK=128 (was 64). Halves the K-tile count (64->32)
// to amortize the per-tile barrier/stall cost that limits GEMM2 to 690 TF
// (its MFMA work per tile is half GEMM1's while per-tile overhead is equal).
// LDS 48KB -> 3 blocks/CU (from 4); grid 32x32 = 1024 blocks.
// 16 k-slots per row; XOR swizzle j^(row&15) on source + read (2-way max = free).
// Epilogue: p=tanh(acc+bias); s=Sout[r][col]; Sout[r][col]=h*(1-s)+p*s
// ---------------------------------------------------------------------------
__global__ void gemm_bt2(const u16* __restrict__ A, const u16* __restrict__ Bm,
                         const float* __restrict__ h,
                         const float* __restrict__ bias0,
                         float* __restrict__ Sout) {
    constexpr int BM = 128, BN = 64, BK = 128;
    const int tid  = threadIdx.x;
    const int lane = tid & 63;
    const int wave = tid >> 6;
    const int wr = wave >> 1, wc = wave & 1;
    const int bm = blockIdx.y * BM;
    const int bn = blockIdx.x * BN;

    __shared__ __align__(16) u16 lA[BM * BK];   // 32 KB
    __shared__ __align__(16) u16 lB[BN * BK];   // 16 KB

    f32x4 acc[4][2] = {};

    // staging: chunk = 16 rows x 128 k = 4KB = one gload_lds16 x 256 threads.
    // thread t -> row ch*16 + (t>>4), src slot (t&15)^(row&15); dest linear:
    // wave base (ch*16 + wave*4)*BK, HW writes lane*16B.
    const int rr = tid >> 4;                        // 0..15
    auto stage = [&](int k0) {
        #pragma unroll
        for (int ch = 0; ch < 8; ++ch) {            // A: 128 rows
            const int r = ch * 16 + rr;
            gload_lds16(A + (size_t)(bm + r) * KDIM + k0 + (((tid & 15) ^ (r & 15)) << 3),
                        &lA[(ch * 16 + wave * 4) * BK]);
        }
        #pragma unroll
        for (int ch = 0; ch < 4; ++ch) {            // B: 64 rows
            const int r = ch * 16 + rr;
            gload_lds16(Bm + (size_t)(bn + r) * KDIM + k0 + (((tid & 15) ^ (r & 15)) << 3),
                        &lB[(ch * 16 + wave * 4) * BK]);
        }
    };

    stage(0);
    constexpr int NT = KDIM / BK;                   // 32
    for (int kt = 0; kt < NT; ++kt) {
        __syncthreads();
        #pragma unroll
        for (int ks = 0; ks < 4; ++ks) {
            s16x8 af[4], bfr[2];
            #pragma unroll
            for (int m = 0; m < 4; ++m) {
                const int row = wr * 64 + m * 16 + (lane & 15);
                const int j   = ks * 4 + (lane >> 4);
                af[m] = *(const s16x8*)&lA[row * BK + ((j ^ (row & 15)) << 3)];
            }
            #pragma unroll
            for (int n = 0; n < 2; ++n) {
                const int row = wc * 32 + n * 16 + (lane & 15);
                const int j   = ks * 4 + (lane >> 4);
                bfr[n] = *(const s16x8*)&lB[row * BK + ((j ^ (row & 15)) << 3)];
            }
            #pragma unroll
            for (int m = 0; m < 4; ++m)
                #pragma unroll
                for (int n = 0; n < 2; ++n)
                    acc[m][n] = __builtin_amdgcn_mfma_f32_16x16x32_bf16(
                        af[m], bfr[n], acc[m][n], 0, 0, 0);
        }
        __syncthreads();
        if (kt + 1 < NT) stage((kt + 1) * BK);
    }

    #pragma unroll
    for (int m = 0; m < 4; ++m) {
        const int r0 = bm + wr * 64 + m * 16 + ((lane >> 4) << 2);
        #pragma unroll
        for (int n = 0; n < 2; ++n) {
            const int col = bn + wc * 32 + n * 16 + (lane & 15);
            #pragma unroll
            for (int j = 0; j < 4; ++j) {
                const int r = r0 + j;
                const float p = tanhf(acc[m][n][j] + bias0[col]);
                const size_t idx = (size_t)r * HDIM + col;
                const float s  = Sout[idx];
                const float hv = h[idx];
                Sout[idx] = hv * (1.0f - s) + p * s;
            }
        }
    }
}

extern "C" void kernel_launch(void* const* d_in, const int* in_sizes, int n_in,
                              void* d_out, int out_size, void* d_ws, size_t ws_size,
                              hipStream_t stream) {
    (void)in_sizes; (void)n_in; (void)out_size; (void)ws_size;
    const float* x  = (const float*)d_in[0];
    const float* h  = (const float*)d_in[1];
    const float* Wu = (const float*)d_in[2];
    const float* bu = (const float*)d_in[3];
    const float* Ws = (const float*)d_in[4];
    const float* bs = (const float*)d_in[5];
    const float* Wp = (const float*)d_in[6];
    const float* bp = (const float*)d_in[7];
    float* out = (float*)d_out;

    // workspace layout (bf16 elements): 112 MB total
    u16* comb  = (u16*)d_ws;                            // [BDIM][CDIM]   32 MB
    u16* newc  = comb  + (size_t)BDIM * CDIM;           // [BDIM][CDIM]   32 MB
    u16* wpack = newc  + (size_t)BDIM * CDIM;           // [2*HDIM][CDIM] 32 MB
    u16* wpred = wpack + (size_t)2 * HDIM * CDIM;       // [HDIM][CDIM]   16 MB

    const int WG = 256;
    const int wgrp = (HDIM * CDIM) / 8;                 // 1M groups per weight
    cvt_bf16_kernel<<<wgrp / WG, WG, 0, stream>>>(Wu, wpack, wgrp);
    cvt_bf16_kernel<<<wgrp / WG, WG, 0, stream>>>(Ws, wpack + (size_t)HDIM * CDIM, wgrp);
    cvt_bf16_kernel<<<wgrp / WG, WG, 0, stream>>>(Wp, wpred, wgrp);
    const int cgrp = (BDIM * CDIM) / 8;                 // 2M groups
    pack_combined_kernel<<<cgrp / WG, WG, 0, stream>>>(x, h, comb, newc);

    // GEMM1: [x,h] @ [Wu;Ws]^T -> sigmoid -> updated (bf16 into newc) + S (f32 into out)
    gemm_bt1<<<dim3(CDIM / 128, BDIM / 128), 256, 0, stream>>>(
        comb, wpack, h, bu, bs, out, newc);
    // GEMM2: [x,updated] @ Wp^T -> tanh -> h_new (f32 into out, reading S in place)
    gemm_bt2<<<dim3(HDIM / 64, BDIM / 128), 256, 0, stream>>>(
        newc, wpred, h, bp, out);
}

// Round 6
// 311.240 us; speedup vs baseline: 1.0119x; 1.0119x over previous
//
#include <hip/hip_runtime.h>
#include <stdint.h>

#define IDIM 2048
#define HDIM 2048
#define CDIM 4096
#define BDIM 4096
#define KDIM 4096

typedef float f32x4 __attribute__((ext_vector_type(4)));
typedef short s16x8 __attribute__((ext_vector_type(8)));
typedef unsigned short u16;
typedef u16 u16x8 __attribute__((ext_vector_type(8)));

__device__ __forceinline__ u16 f2bf(float f) {
    union { float f; uint32_t u; } v; v.f = f;
    uint32_t r = v.u + 0x7fffu + ((v.u >> 16) & 1u);  // round-to-nearest-even
    return (u16)(r >> 16);
}

__device__ __forceinline__ void gload_lds16(const void* g, void* l) {
    __builtin_amdgcn_global_load_lds(
        (__attribute__((address_space(1))) void*)g,
        (__attribute__((address_space(3))) void*)l,
        16, 0, 0);
}

// flat f32 -> bf16 convert, 8 elements per thread
__global__ void cvt_bf16_kernel(const float* __restrict__ src, u16* __restrict__ dst,
                                int ngroups) {
    int i = blockIdx.x * blockDim.x + threadIdx.x;
    if (i >= ngroups) return;
    const float4* s4 = (const float4*)src;
    float4 v0 = s4[2 * i], v1 = s4[2 * i + 1];
    u16x8 o;
    o[0] = f2bf(v0.x); o[1] = f2bf(v0.y); o[2] = f2bf(v0.z); o[3] = f2bf(v0.w);
    o[4] = f2bf(v1.x); o[5] = f2bf(v1.y); o[6] = f2bf(v1.z); o[7] = f2bf(v1.w);
    ((u16x8*)dst)[i] = o;
}

// combined = [x, h] as bf16 [BDIM][CDIM]; also pre-fill new_combined's x half
__global__ void pack_combined_kernel(const float* __restrict__ x, const float* __restrict__ h,
                                     u16* __restrict__ comb, u16* __restrict__ newc) {
    int i = blockIdx.x * blockDim.x + threadIdx.x;  // one group of 8 elems
    if (i >= BDIM * (CDIM / 8)) return;
    int b = i >> 9;              // CDIM/8 == 512
    int c = (i & 511) * 8;
    const float* src = (c < IDIM) ? (x + (size_t)b * IDIM + c)
                                  : (h + (size_t)b * HDIM + (c - IDIM));
    float4 v0 = ((const float4*)src)[0], v1 = ((const float4*)src)[1];
    u16x8 o;
    o[0] = f2bf(v0.x); o[1] = f2bf(v0.y); o[2] = f2bf(v0.z); o[3] = f2bf(v0.w);
    o[4] = f2bf(v1.x); o[5] = f2bf(v1.y); o[6] = f2bf(v1.z); o[7] = f2bf(v1.w);
    *(u16x8*)(comb + (size_t)b * CDIM + c) = o;
    if (c < IDIM) *(u16x8*)(newc + (size_t)b * CDIM + c) = o;
}

// ---------------------------------------------------------------------------
// Split-K-in-block GEMM: C = A[M,K]*B[N,K]^T. 128x128 tile, BK=128, 8 waves
// (2m x 2n x 2 k-groups, 512 thr). Each wave: 64x64 quadrant over a 64-wide
// K-half -> per-step wave work IDENTICAL to the proven round-3 loop (16
// ds_read_b128 : 32 MFMA), but 32 steps instead of 64 (half the barrier-drain
// events F) and 16 waves/CU preserved (LDS 64KB -> 2 blocks/CU x 8 waves;
// dodges the m132 BK=128 occupancy trap). End: kg1 waves dump acc into the
// dead LDS, kg0 adds (f32 add commutative -> deterministic) + epilogue.
// 16-slot XOR swizzle (j ^ row&15) on source + read.
// EP==1: v=sigmoid(acc+bias); col<HDIM -> newc[r][IDIM+col]=bf16(h*v);
//        col>=HDIM -> Sout[r][col-HDIM]=v
// EP==2: p=tanh(acc+bias0); s=Sout[r][col]; Sout[r][col]=h*(1-s)+p*s
// ---------------------------------------------------------------------------
template <int EP>
__global__ __launch_bounds__(512, 4) void gemm_sk(
        const u16* __restrict__ A, const u16* __restrict__ Bm,
        const float* __restrict__ h,
        const float* __restrict__ bias0, const float* __restrict__ bias1,
        float* __restrict__ Sout, u16* __restrict__ newc) {
    constexpr int BK = 128, NT = KDIM / BK;   // 32 steps
    const int tid  = threadIdx.x;
    const int lane = tid & 63;
    const int wave = tid >> 6;
    const int kg = wave >> 2;                 // k-group: 0 -> k 0..63, 1 -> 64..127
    const int wq = wave & 3;
    const int wr = wq >> 1, wc = wq & 1;
    const int bm = blockIdx.y * 128;
    const int bn = blockIdx.x * 128;

    __shared__ __align__(16) u16 smem[2 * 128 * 128];   // 64KB: A tile, B tile
    u16* lA = smem;
    u16* lB = smem + 128 * 128;

    f32x4 acc[4][4] = {};

    // staging: chunk = 32 rows x 128 k = 8KB = one gload_lds16 x 512 threads.
    // thread t -> row c*32 + (t>>4), source slot (t&15)^(row&15); dest linear
    // (c*32 + wave*4)*128 => byte off = c*8192 + wave*1024 + lane*16. ✓
    const int srow  = tid >> 4;                               // 0..31
    const int sslot = ((tid & 15) ^ (srow & 15)) << 3;        // elem offset

    auto stage = [&](int k0) {
        #pragma unroll
        for (int c = 0; c < 4; ++c)
            gload_lds16(A + (size_t)(bm + c * 32 + srow) * KDIM + k0 + sslot,
                        &lA[(c * 32 + wave * 4) * 128]);
        #pragma unroll
        for (int c = 0; c < 4; ++c)
            gload_lds16(Bm + (size_t)(bn + c * 32 + srow) * KDIM + k0 + sslot,
                        &lB[(c * 32 + wave * 4) * 128]);
    };

    stage(0);
    for (int kt = 0; kt < NT; ++kt) {
        __syncthreads();   // drains global_load_lds (vmcnt) + all waves ready
        #pragma unroll
        for (int ks = 0; ks < 2; ++ks) {
            s16x8 af[4], bfr[4];
            #pragma unroll
            for (int m = 0; m < 4; ++m) {
                const int row = wr * 64 + m * 16 + (lane & 15);
                const int j   = kg * 8 + ks * 4 + (lane >> 4);
                af[m] = *(const s16x8*)&lA[row * 128 + ((j ^ (row & 15)) << 3)];
            }
            #pragma unroll
            for (int n = 0; n < 4; ++n) {
                const int row = wc * 64 + n * 16 + (lane & 15);
                const int j   = kg * 8 + ks * 4 + (lane >> 4);
                bfr[n] = *(const s16x8*)&lB[row * 128 + ((j ^ (row & 15)) << 3)];
            }
            #pragma unroll
            for (int m = 0; m < 4; ++m)
                #pragma unroll
                for (int n = 0; n < 4; ++n)
                    acc[m][n] = __builtin_amdgcn_mfma_f32_16x16x32_bf16(
                        af[m], bfr[n], acc[m][n], 0, 0, 0);
        }
        __syncthreads();   // all reads done before restage
        if (kt + 1 < NT) stage((kt + 1) * BK);
    }
    // (loop's final __syncthreads guarantees all LDS reads done -> safe to reuse)

    // split-K reduction: kg1 dumps acc into LDS (lane-interleaved, 16KB/wave),
    // kg0 adds. Deterministic: exactly one add order per element.
    f32x4* red = (f32x4*)smem;                // 4096 f32x4 = 64KB
    if (kg == 1) {
        #pragma unroll
        for (int m = 0; m < 4; ++m)
            #pragma unroll
            for (int n = 0; n < 4; ++n)
                red[wq * 1024 + (m * 4 + n) * 64 + lane] = acc[m][n];
    }
    __syncthreads();
    if (kg == 0) {
        #pragma unroll
        for (int m = 0; m < 4; ++m)
            #pragma unroll
            for (int n = 0; n < 4; ++n)
                acc[m][n] += red[wq * 1024 + (m * 4 + n) * 64 + lane];

        // epilogue: D layout col = lane&15, row = (lane>>4)*4 + reg (m89-verified)
        #pragma unroll
        for (int m = 0; m < 4; ++m) {
            const int r0 = bm + wr * 64 + m * 16 + ((lane >> 4) << 2);
            #pragma unroll
            for (int n = 0; n < 4; ++n) {
                const int col = bn + wc * 64 + n * 16 + (lane & 15);
                #pragma unroll
                for (int j = 0; j < 4; ++j) {
                    const int r = r0 + j;
                    const float v = acc[m][n][j];
                    if constexpr (EP == 1) {
                        const float bv = (col < HDIM) ? bias0[col] : bias1[col - HDIM];
                        const float sgm = 1.0f / (1.0f + __expf(-(v + bv)));
                        if (col < HDIM) {
                            const float hv = h[(size_t)r * HDIM + col];
                            newc[(size_t)r * CDIM + IDIM + col] = f2bf(hv * sgm);
                        } else {
                            Sout[(size_t)r * HDIM + (col - HDIM)] = sgm;
                        }
                    } else {
                        const float p = tanhf(v + bias0[col]);
                        const size_t idx = (size_t)r * HDIM + col;
                        const float s  = Sout[idx];
                        const float hv = h[idx];
                        Sout[idx] = hv * (1.0f - s) + p * s;
                    }
                }
            }
        }
    }
}

extern "C" void kernel_launch(void* const* d_in, const int* in_sizes, int n_in,
                              void* d_out, int out_size, void* d_ws, size_t ws_size,
                              hipStream_t stream) {
    (void)in_sizes; (void)n_in; (void)out_size; (void)ws_size;
    const float* x  = (const float*)d_in[0];
    const float* h  = (const float*)d_in[1];
    const float* Wu = (const float*)d_in[2];
    const float* bu = (const float*)d_in[3];
    const float* Ws = (const float*)d_in[4];
    const float* bs = (const float*)d_in[5];
    const float* Wp = (const float*)d_in[6];
    const float* bp = (const float*)d_in[7];
    float* out = (float*)d_out;

    // workspace layout (bf16 elements): 112 MB total
    u16* comb  = (u16*)d_ws;                            // [BDIM][CDIM]   32 MB
    u16* newc  = comb  + (size_t)BDIM * CDIM;           // [BDIM][CDIM]   32 MB
    u16* wpack = newc  + (size_t)BDIM * CDIM;           // [2*HDIM][CDIM] 32 MB
    u16* wpred = wpack + (size_t)2 * HDIM * CDIM;       // [HDIM][CDIM]   16 MB

    const int WG = 256;
    const int wgrp = (HDIM * CDIM) / 8;                 // 1M groups per weight
    cvt_bf16_kernel<<<wgrp / WG, WG, 0, stream>>>(Wu, wpack, wgrp);
    cvt_bf16_kernel<<<wgrp / WG, WG, 0, stream>>>(Ws, wpack + (size_t)HDIM * CDIM, wgrp);
    cvt_bf16_kernel<<<wgrp / WG, WG, 0, stream>>>(Wp, wpred, wgrp);
    const int cgrp = (BDIM * CDIM) / 8;                 // 2M groups
    pack_combined_kernel<<<cgrp / WG, WG, 0, stream>>>(x, h, comb, newc);

    // GEMM1: [x,h] @ [Wu;Ws]^T -> sigmoid -> updated (bf16 into newc) + S (f32 into out)
    gemm_sk<1><<<dim3(CDIM / 128, BDIM / 128), 512, 0, stream>>>(
        comb, wpack, h, bu, bs, out, newc);
    // GEMM2: [x,updated] @ Wp^T -> tanh -> h_new (f32 into out, reading S in place)
    gemm_sk<2><<<dim3(HDIM / 128, BDIM / 128), 512, 0, stream>>>(
        newc, wpred, h, bp, nullptr, out, nullptr);
}

// Round 7
// 290.193 us; speedup vs baseline: 1.0853x; 1.0725x over previous
//
#include <hip/hip_runtime.h>
#include <stdint.h>

#define IDIM 2048
#define HDIM 2048
#define CDIM 4096
#define BDIM 4096
#define KDIM 4096

typedef float f32x4 __attribute__((ext_vector_type(4)));
typedef short s16x8 __attribute__((ext_vector_type(8)));
typedef unsigned short u16;
typedef u16 u16x8 __attribute__((ext_vector_type(8)));

__device__ __forceinline__ u16 f2bf(float f) {
    union { float f; uint32_t u; } v; v.f = f;
    uint32_t r = v.u + 0x7fffu + ((v.u >> 16) & 1u);  // round-to-nearest-even
    return (u16)(r >> 16);
}

__device__ __forceinline__ u16x8 cvt8(float4 v0, float4 v1) {
    u16x8 o;
    o[0] = f2bf(v0.x); o[1] = f2bf(v0.y); o[2] = f2bf(v0.z); o[3] = f2bf(v0.w);
    o[4] = f2bf(v1.x); o[5] = f2bf(v1.y); o[6] = f2bf(v1.z); o[7] = f2bf(v1.w);
    return o;
}

__device__ __forceinline__ void gload_lds16(const void* g, void* l) {
    __builtin_amdgcn_global_load_lds(
        (__attribute__((address_space(1))) void*)g,
        (__attribute__((address_space(3))) void*)l,
        16, 0, 0);
}

// merged prep: Wu cvt (1M groups) + Ws cvt (1M) + pack_combined (2M).
// one launch instead of three.
__global__ void prep_kernel(const float* __restrict__ x, const float* __restrict__ h,
                            const float* __restrict__ Wu, const float* __restrict__ Ws,
                            u16* __restrict__ comb, u16* __restrict__ newc,
                            u16* __restrict__ wpack) {
    const int WCNT = (HDIM * CDIM) / 8;             // 1M groups per weight
    int i = blockIdx.x * blockDim.x + threadIdx.x;  // 0..4M-1
    if (i < 2 * WCNT) {
        const float* src = (i < WCNT) ? Wu : Ws;
        const int g = (i < WCNT) ? i : i - WCNT;
        u16* dst = wpack + (i < WCNT ? (size_t)0 : (size_t)HDIM * CDIM);
        const float4* s4 = (const float4*)src;
        ((u16x8*)dst)[g] = cvt8(s4[2 * g], s4[2 * g + 1]);
    } else {
        const int p = i - 2 * WCNT;                 // 0..2M-1
        const int b = p >> 9;                       // CDIM/8 == 512
        const int c = (p & 511) * 8;
        const float* src = (c < IDIM) ? (x + (size_t)b * IDIM + c)
                                      : (h + (size_t)b * HDIM + (c - IDIM));
        u16x8 o = cvt8(((const float4*)src)[0], ((const float4*)src)[1]);
        *(u16x8*)(comb + (size_t)b * CDIM + c) = o;
        if (c < IDIM) *(u16x8*)(newc + (size_t)b * CDIM + c) = o;
    }
}

// ---------------------------------------------------------------------------
// GEMM1 (proven 149us / 899 TF): m97 structure, 128x128 tile, BK=64, 4 waves,
// wave tile 64x64. NO xcd swizzle (round-5: it doubled FETCH_SIZE — the
// natural dispatch already round-robins XCDs; remapping scattered panels).
// Fold: each block also converts a disjoint 32KB slice of Wp (f32->bf16) at
// the end — hides the separate cvt kernel (~10us) under GEMM1's BW headroom.
// Epilogue: v=sigmoid(acc+bias); col<HDIM -> newc[r][IDIM+col]=bf16(h*v);
//           col>=HDIM -> Sout[r][col-HDIM]=v
// ---------------------------------------------------------------------------
__global__ void gemm_bt1(const u16* __restrict__ A, const u16* __restrict__ Bm,
                         const float* __restrict__ h,
                         const float* __restrict__ bias0, const float* __restrict__ bias1,
                         float* __restrict__ Sout, u16* __restrict__ newc,
                         const float* __restrict__ Wp, u16* __restrict__ wpred) {
    constexpr int BM = 128, BK = 64;
    const int tid  = threadIdx.x;
    const int lane = tid & 63;
    const int wave = tid >> 6;
    const int wr = wave >> 1, wc = wave & 1;
    const int bm = blockIdx.y * BM;
    const int bn = blockIdx.x * BM;

    __shared__ __align__(16) u16 lA[BM * BK];
    __shared__ __align__(16) u16 lB[BM * BK];

    f32x4 acc[4][4] = {};

    const int srow = wave * 32 + (lane >> 3);       // staged row (per i: +8*i)
    const int sg   = (lane & 7) ^ (lane >> 3);      // swizzled source k-slot

    auto stage = [&](int k0) {
        #pragma unroll
        for (int i = 0; i < 4; ++i) {
            const int r = srow + i * 8;
            gload_lds16(A  + (size_t)(bm + r) * KDIM + k0 + sg * 8,
                        &lA[(wave * 32 + i * 8) * 64]);
            gload_lds16(Bm + (size_t)(bn + r) * KDIM + k0 + sg * 8,
                        &lB[(wave * 32 + i * 8) * 64]);
        }
    };

    stage(0);
    constexpr int NT = KDIM / BK;
    for (int kt = 0; kt < NT; ++kt) {
        __syncthreads();   // drains global_load_lds (vmcnt) + all waves ready
        #pragma unroll
        for (int ks = 0; ks < 2; ++ks) {
            s16x8 af[4], bfr[4];
            #pragma unroll
            for (int m = 0; m < 4; ++m) {
                const int row = wr * 64 + m * 16 + (lane & 15);
                const int j   = ks * 4 + (lane >> 4);
                af[m] = *(const s16x8*)&lA[row * 64 + ((j ^ (row & 7)) << 3)];
            }
            #pragma unroll
            for (int n = 0; n < 4; ++n) {
                const int row = wc * 64 + n * 16 + (lane & 15);
                const int j   = ks * 4 + (lane >> 4);
                bfr[n] = *(const s16x8*)&lB[row * 64 + ((j ^ (row & 7)) << 3)];
            }
            #pragma unroll
            for (int m = 0; m < 4; ++m)
                #pragma unroll
                for (int n = 0; n < 4; ++n)
                    acc[m][n] = __builtin_amdgcn_mfma_f32_16x16x32_bf16(
                        af[m], bfr[n], acc[m][n], 0, 0, 0);
        }
        __syncthreads();   // all reads done before restage
        if (kt + 1 < NT) stage((kt + 1) * BK);
    }

    // epilogue: D layout col = lane&15, row = (lane>>4)*4 + reg (m89-verified)
    #pragma unroll
    for (int m = 0; m < 4; ++m) {
        const int r0 = bm + wr * 64 + m * 16 + ((lane >> 4) << 2);
        #pragma unroll
        for (int n = 0; n < 4; ++n) {
            const int col = bn + wc * 64 + n * 16 + (lane & 15);
            #pragma unroll
            for (int j = 0; j < 4; ++j) {
                const int r = r0 + j;
                const float v = acc[m][n][j];
                const float bv = (col < HDIM) ? bias0[col] : bias1[col - HDIM];
                const float sgm = 1.0f / (1.0f + __expf(-(v + bv)));
                if (col < HDIM) {
                    const float hv = h[(size_t)r * HDIM + col];
                    newc[(size_t)r * CDIM + IDIM + col] = f2bf(hv * sgm);
                } else {
                    Sout[(size_t)r * HDIM + (col - HDIM)] = sgm;
                }
            }
        }
    }

    // folded Wp convert: block bid owns floats [bid*8192, bid*8192+8192)
    {
        const int bid = blockIdx.y * (CDIM / 128) + blockIdx.x;   // 0..1023
        const size_t base = (size_t)bid * 8192;
        const float4* s4 = (const float4*)(Wp + base);
        u16x8* d8 = (u16x8*)(wpred + base);
        #pragma unroll
        for (int t = 0; t < 4; ++t) {
            const int g = t * 256 + tid;                          // 0..1023
            d8[g] = cvt8(s4[2 * g], s4[2 * g + 1]);
        }
    }
}

// ---------------------------------------------------------------------------
// GEMM2 v3: 128x64 block, BK=64, TWO waves (128 thr) M-split -> wave tile
// 64x64 (reads:MFMA = 0.5, same as GEMM1 — round-3's 64x32 wave tile was
// LDS-BW-bound: 192KB/CU/step = 1500cy > 1242cy MFMA). Grid 32x32 = 1024
// blocks; LDS 24KB + ~124 regs -> up to 6 blocks/CU (launch_bounds(128,3)).
// B LDS reads duplicate across the 2 waves (inside the 0.5 ratio).
// Epilogue: p=tanh(acc+bias); s=Sout[r][col]; Sout[r][col]=h*(1-s)+p*s
// ---------------------------------------------------------------------------
__global__ __launch_bounds__(128, 3) void gemm_bt2(
        const u16* __restrict__ A, const u16* __restrict__ Bm,
        const float* __restrict__ h, const float* __restrict__ bias0,
        float* __restrict__ Sout) {
    constexpr int BM = 128, BN = 64, BK = 64;
    const int tid  = threadIdx.x;                   // 0..127
    const int lane = tid & 63;
    const int wave = tid >> 6;                      // M-split: rows wave*64..+63
    const int bm = blockIdx.y * BM;
    const int bn = blockIdx.x * BN;

    __shared__ __align__(16) u16 lA[BM * BK];       // 16KB
    __shared__ __align__(16) u16 lB[BN * BK];       // 8KB

    f32x4 acc[4][4] = {};

    // staging: chunk = 16 rows x 64k = 2KB = 128 threads x 16B.
    // thread t -> row c*16 + (t>>3), slot t&7, src swizzle (t&7)^(row&7).
    // dest: wave-uniform base &l[(c*16 + wave*8)*64], HW adds lane*16B. ✓
    const int srow = tid >> 3;                      // 0..15
    const int ssw  = ((tid & 7) ^ (srow & 7)) << 3;

    auto stage = [&](int k0) {
        #pragma unroll
        for (int c = 0; c < 8; ++c)                 // A: 128 rows
            gload_lds16(A + (size_t)(bm + c * 16 + srow) * KDIM + k0 + ssw,
                        &lA[(c * 16 + wave * 8) * 64]);
        #pragma unroll
        for (int c = 0; c < 4; ++c)                 // B: 64 rows
            gload_lds16(Bm + (size_t)(bn + c * 16 + srow) * KDIM + k0 + ssw,
                        &lB[(c * 16 + wave * 8) * 64]);
    };

    stage(0);
    constexpr int NT = KDIM / BK;
    for (int kt = 0; kt < NT; ++kt) {
        __syncthreads();
        #pragma unroll
        for (int ks = 0; ks < 2; ++ks) {
            s16x8 af[4], bfr[4];
            #pragma unroll
            for (int m = 0; m < 4; ++m) {
                const int row = wave * 64 + m * 16 + (lane & 15);
                const int j   = ks * 4 + (lane >> 4);
                af[m] = *(const s16x8*)&lA[row * 64 + ((j ^ (row & 7)) << 3)];
            }
            #pragma unroll
            for (int n = 0; n < 4; ++n) {
                const int row = n * 16 + (lane & 15);
                const int j   = ks * 4 + (lane >> 4);
                bfr[n] = *(const s16x8*)&lB[row * 64 + ((j ^ (row & 7)) << 3)];
            }
            #pragma unroll
            for (int m = 0; m < 4; ++m)
                #pragma unroll
                for (int n = 0; n < 4; ++n)
                    acc[m][n] = __builtin_amdgcn_mfma_f32_16x16x32_bf16(
                        af[m], bfr[n], acc[m][n], 0, 0, 0);
        }
        __syncthreads();
        if (kt + 1 < NT) stage((kt + 1) * BK);
    }

    #pragma unroll
    for (int m = 0; m < 4; ++m) {
        const int r0 = bm + wave * 64 + m * 16 + ((lane >> 4) << 2);
        #pragma unroll
        for (int n = 0; n < 4; ++n) {
            const int col = bn + n * 16 + (lane & 15);
            #pragma unroll
            for (int j = 0; j < 4; ++j) {
                const int r = r0 + j;
                const float p = tanhf(acc[m][n][j] + bias0[col]);
                const size_t idx = (size_t)r * HDIM + col;
                const float s  = Sout[idx];
                const float hv = h[idx];
                Sout[idx] = hv * (1.0f - s) + p * s;
            }
        }
    }
}

extern "C" void kernel_launch(void* const* d_in, const int* in_sizes, int n_in,
                              void* d_out, int out_size, void* d_ws, size_t ws_size,
                              hipStream_t stream) {
    (void)in_sizes; (void)n_in; (void)out_size; (void)ws_size;
    const float* x  = (const float*)d_in[0];
    const float* h  = (const float*)d_in[1];
    const float* Wu = (const float*)d_in[2];
    const float* bu = (const float*)d_in[3];
    const float* Ws = (const float*)d_in[4];
    const float* bs = (const float*)d_in[5];
    const float* Wp = (const float*)d_in[6];
    const float* bp = (const float*)d_in[7];
    float* out = (float*)d_out;

    // workspace layout (bf16 elements): 112 MB total
    u16* comb  = (u16*)d_ws;                            // [BDIM][CDIM]   32 MB
    u16* newc  = comb  + (size_t)BDIM * CDIM;           // [BDIM][CDIM]   32 MB
    u16* wpack = newc  + (size_t)BDIM * CDIM;           // [2*HDIM][CDIM] 32 MB
    u16* wpred = wpack + (size_t)2 * HDIM * CDIM;       // [HDIM][CDIM]   16 MB

    // prep: Wu+Ws cvt + pack_combined, one kernel (4M groups of 8 elems)
    const int ngrp = 2 * ((HDIM * CDIM) / 8) + (BDIM * CDIM) / 8;   // 4M
    prep_kernel<<<ngrp / 256, 256, 0, stream>>>(x, h, Wu, Ws, comb, newc, wpack);

    // GEMM1: [x,h] @ [Wu;Ws]^T -> sigmoid -> updated (bf16 into newc) + S (f32
    // into out); also converts Wp -> wpred (folded).
    gemm_bt1<<<dim3(CDIM / 128, BDIM / 128), 256, 0, stream>>>(
        comb, wpack, h, bu, bs, out, newc, Wp, wpred);
    // GEMM2: [x,updated] @ Wp^T -> tanh -> h_new (f32 into out, reading S in place)
    gemm_bt2<<<dim3(HDIM / 64, BDIM / 128), 128, 0, stream>>>(
        newc, wpred, h, bp, out);
}